// Round 1
// baseline (1053.741 us; speedup 1.0000x reference)
//
#include <hip/hip_runtime.h>
#include <hip/hip_bf16.h>
#include <math.h>

#define N_NODES 50000
#define FDIM 64
#define BETA 0.5f
#define NEG_SLOPE 0.2f

// ---------------------------------------------------------------------------
// Detect whether edge_index is int64 (high dwords all zero) or int32.
// flag==1 -> int32 data, flag==0 -> int64 data.
__global__ void detect_kernel(const unsigned int* __restrict__ ei, int* flag, int nCheck) {
    int i = blockIdx.x * blockDim.x + threadIdx.x;
    if (i < nCheck) {
        if (ei[2 * i + 1] != 0u) atomicOr(flag, 1);
    }
}

// Count in-degree per dst.
__global__ void count_kernel(const int* __restrict__ ei32, const long long* __restrict__ ei64,
                             const int* __restrict__ flag, int* __restrict__ counts, int E) {
    int i = blockIdx.x * blockDim.x + threadIdx.x;
    if (i >= E) return;
    int d = (*flag) ? ei32[E + i] : (int)ei64[E + i];
    atomicAdd(&counts[d], 1);
}

// Single-block exclusive scan over counts -> offsets (and cursor copy).
__global__ __launch_bounds__(1024) void scan_kernel(const int* __restrict__ counts,
                                                    int* __restrict__ offsets,
                                                    int* __restrict__ cursor, int N) {
    __shared__ int sums[1024];
    int t = threadIdx.x;
    const int CH = (N + 1023) / 1024;
    int base = t * CH;
    int s = 0;
    for (int i = 0; i < CH; i++) {
        int idx = base + i;
        if (idx < N) s += counts[idx];
    }
    sums[t] = s;
    __syncthreads();
    for (int off = 1; off < 1024; off <<= 1) {
        int v = (t >= off) ? sums[t - off] : 0;
        __syncthreads();
        sums[t] += v;
        __syncthreads();
    }
    int run = (t == 0) ? 0 : sums[t - 1];
    for (int i = 0; i < CH; i++) {
        int idx = base + i;
        if (idx < N) {
            int c = counts[idx];
            offsets[idx] = run;
            cursor[idx]  = run;
            run += c;
        }
    }
    if (t == 1023) offsets[N] = run;
}

// Scatter edge srcs into dst-sorted order.
__global__ void fill_kernel(const int* __restrict__ ei32, const long long* __restrict__ ei64,
                            const int* __restrict__ flag, int* __restrict__ cursor,
                            int* __restrict__ srcs_sorted, int E) {
    int i = blockIdx.x * blockDim.x + threadIdx.x;
    if (i >= E) return;
    int s, d;
    if (*flag) { s = ei32[i]; d = ei32[E + i]; }
    else       { s = (int)ei64[i]; d = (int)ei64[E + i]; }
    int pos = atomicAdd(&cursor[d], 1);
    srcs_sorted[pos] = s;
}

// ---------------------------------------------------------------------------
// h = x @ W (+ bias); optionally as_ = h.a_src, ad_ = h.a_dst per node.
// block = 256 threads = 4 waves; wave = one ty slice, lane = output feature f.
// 32 nodes per block, 8 nodes per thread.
__global__ __launch_bounds__(256) void node_transform(
    const float* __restrict__ x, const float* __restrict__ W,
    const float* __restrict__ bias,                    // nullable
    const float* __restrict__ a_src, const float* __restrict__ a_dst,  // nullable pair
    float* __restrict__ h, float* __restrict__ as_, float* __restrict__ ad_, int N) {
    __shared__ __align__(16) float Ws[64 * 64];
    __shared__ __align__(16) float xs[32 * 64];
    int tid = threadIdx.x;
    int f = tid & 63;
    int ty = tid >> 6;
    for (int i = tid; i < 64 * 64; i += 256) Ws[i] = W[i];
    int nodeBase = blockIdx.x * 32;
    for (int i = tid; i < 32 * 64; i += 256) {
        int n = nodeBase + (i >> 6);
        xs[i] = (n < N) ? x[(size_t)n * FDIM + (i & 63)] : 0.f;
    }
    __syncthreads();

    float acc[8];
#pragma unroll
    for (int j = 0; j < 8; j++) acc[j] = 0.f;

#pragma unroll
    for (int k = 0; k < 64; k += 4) {
        float w0 = Ws[(k + 0) * 64 + f];
        float w1 = Ws[(k + 1) * 64 + f];
        float w2 = Ws[(k + 2) * 64 + f];
        float w3 = Ws[(k + 3) * 64 + f];
#pragma unroll
        for (int j = 0; j < 8; j++) {
            float4 xv = *(const float4*)&xs[(ty + 4 * j) * 64 + k];
            acc[j] += xv.x * w0 + xv.y * w1 + xv.z * w2 + xv.w * w3;
        }
    }

    float bv = bias ? bias[f] : 0.f;
    float asf = a_src ? a_src[f] : 0.f;
    float adf = a_dst ? a_dst[f] : 0.f;
#pragma unroll
    for (int j = 0; j < 8; j++) {
        int n = nodeBase + ty + 4 * j;
        float hv = acc[j] + bv;
        if (n < N) h[(size_t)n * FDIM + f] = hv;
        if (a_src) {
            float v1 = acc[j] * asf;
            float v2 = acc[j] * adf;
            for (int off = 32; off; off >>= 1) {
                v1 += __shfl_down(v1, off, 64);
                v2 += __shfl_down(v2, off, 64);
            }
            if (f == 0 && n < N) { as_[n] = v1; ad_[n] = v2; }
        }
    }
}

// ---------------------------------------------------------------------------
// One wave per dst node: softmax over incoming edges + weighted feature sum.
// lane = feature index. xout[dst] = BETA*(sum_w*h/denom + b) + (1-BETA)*x0[dst]
__global__ __launch_bounds__(256) void gat_gather(
    const float* __restrict__ h, const float* __restrict__ as_, const float* __restrict__ ad_,
    const int* __restrict__ offsets, const int* __restrict__ srcs,
    const float* __restrict__ bvec, const float* __restrict__ x0,
    float* __restrict__ xout, int N) {
    int wave = (blockIdx.x * blockDim.x + threadIdx.x) >> 6;
    int lane = threadIdx.x & 63;
    if (wave >= N) return;
    int dst = wave;
    int beg = offsets[dst], end = offsets[dst + 1];
    float adv = ad_[dst];

    // pass 1: max logit
    float m = -INFINITY;
    for (int i = beg + lane; i < end; i += 64) {
        int s = srcs[i];
        float e = as_[s] + adv;
        e = e > 0.f ? e : NEG_SLOPE * e;
        m = fmaxf(m, e);
    }
#pragma unroll
    for (int off = 32; off; off >>= 1) m = fmaxf(m, __shfl_xor(m, off, 64));

    // pass 2: fused exp-sum + weighted feature accumulation
    float acc = 0.f, denom = 0.f;
    for (int cbeg = beg; cbeg < end; cbeg += 64) {
        int i = cbeg + lane;
        float ex = 0.f;
        int s = 0;
        if (i < end) {
            s = srcs[i];
            float e = as_[s] + adv;
            e = e > 0.f ? e : NEG_SLOPE * e;
            ex = __expf(e - m);
        }
        denom += ex;
        int cnt = min(64, end - cbeg);
        for (int t = 0; t < cnt; t++) {
            float exj = __shfl(ex, t, 64);
            int sj = __shfl(s, t, 64);
            acc += exj * h[(size_t)sj * FDIM + lane];
        }
    }
#pragma unroll
    for (int off = 32; off; off >>= 1) denom += __shfl_xor(denom, off, 64);

    float inv = denom > 0.f ? 1.f / denom : 0.f;
    float outv = BETA * (acc * inv + bvec[lane]) + (1.f - BETA) * x0[(size_t)dst * FDIM + lane];
    xout[(size_t)dst * FDIM + lane] = outv;
}

// ---------------------------------------------------------------------------
extern "C" void kernel_launch(void* const* d_in, const int* in_sizes, int n_in,
                              void* d_out, int out_size, void* d_ws, size_t ws_size,
                              hipStream_t stream) {
    const int N = N_NODES;
    const int E = in_sizes[1] / 2;

    const float* x     = (const float*)d_in[0];
    const void*  ei    = d_in[1];
    const float* W     = (const float*)d_in[2];
    const float* a_src = (const float*)d_in[3];
    const float* a_dst = (const float*)d_in[4];
    const float* bvec  = (const float*)d_in[5];
    const float* fc_w  = (const float*)d_in[6];
    const float* fc_b  = (const float*)d_in[7];

    float* out = (float*)d_out;                 // [N, F]
    float* x3  = out + (size_t)N * FDIM;        // [N, F] (second output = h)

    char* p = (char*)d_ws;
    auto alloc = [&](size_t bytes) -> void* {
        void* r = (void*)p;
        p += (bytes + 255) & ~(size_t)255;
        return r;
    };
    int*   flag    = (int*)alloc(256);
    int*   counts  = (int*)alloc((size_t)N * 4);
    int*   offsets = (int*)alloc((size_t)(N + 1) * 4);
    int*   cursor  = (int*)alloc((size_t)N * 4);
    int*   srcs    = (int*)alloc((size_t)E * 4);
    float* h       = (float*)alloc((size_t)N * FDIM * 4);
    float* as_     = (float*)alloc((size_t)N * 4);
    float* ad_     = (float*)alloc((size_t)N * 4);
    float* xbuf    = (float*)alloc((size_t)N * FDIM * 4);

    hipMemsetAsync(flag, 0, 4, stream);
    hipMemsetAsync(counts, 0, (size_t)N * 4, stream);

    const int nCheck = 65536;
    detect_kernel<<<nCheck / 256, 256, 0, stream>>>((const unsigned int*)ei, flag, nCheck);

    int egrid = (E + 255) / 256;
    count_kernel<<<egrid, 256, 0, stream>>>((const int*)ei, (const long long*)ei, flag, counts, E);
    scan_kernel<<<1, 1024, 0, stream>>>(counts, offsets, cursor, N);
    fill_kernel<<<egrid, 256, 0, stream>>>((const int*)ei, (const long long*)ei, flag, cursor, srcs, E);

    int tgrid = (N + 31) / 32;
    int ggrid = (N * 64 + 255) / 256;

    // layer 1
    node_transform<<<tgrid, 256, 0, stream>>>(x, W, nullptr, a_src, a_dst, h, as_, ad_, N);
    gat_gather<<<ggrid, 256, 0, stream>>>(h, as_, ad_, offsets, srcs, bvec, x, xbuf, N);
    // layer 2
    node_transform<<<tgrid, 256, 0, stream>>>(xbuf, W, nullptr, a_src, a_dst, h, as_, ad_, N);
    gat_gather<<<ggrid, 256, 0, stream>>>(h, as_, ad_, offsets, srcs, bvec, x, xbuf, N);
    // layer 3
    node_transform<<<tgrid, 256, 0, stream>>>(xbuf, W, nullptr, a_src, a_dst, h, as_, ad_, N);
    gat_gather<<<ggrid, 256, 0, stream>>>(h, as_, ad_, offsets, srcs, bvec, x, x3, N);
    // final fc: out = x3 @ fc_w + fc_b
    node_transform<<<tgrid, 256, 0, stream>>>(x3, fc_w, fc_b, nullptr, nullptr, out, nullptr, nullptr, N);
}

// Round 2
// 668.898 us; speedup vs baseline: 1.5753x; 1.5753x over previous
//
#include <hip/hip_runtime.h>
#include <hip/hip_bf16.h>
#include <math.h>

#define N_NODES 50000
#define FDIM 64
#define BETA 0.5f
#define NEG_SLOPE 0.2f

// ---------------------------------------------------------------------------
// Detect whether edge_index is int64 (high dwords all zero) or int32.
// flag==1 -> int32 data, flag==0 -> int64 data.
__global__ void detect_kernel(const unsigned int* __restrict__ ei, int* flag, int nCheck) {
    int i = blockIdx.x * blockDim.x + threadIdx.x;
    if (i < nCheck) {
        if (ei[2 * i + 1] != 0u) atomicOr(flag, 1);
    }
}

// LDS-aggregated histogram of dst buckets (bucket = dst>>8).
__global__ __launch_bounds__(256) void hist_kernel(
    const int* __restrict__ ei32, const long long* __restrict__ ei64,
    const int* __restrict__ flag, int* __restrict__ bucketCounts, int E) {
    __shared__ int h[256];
    int t = threadIdx.x;
    h[t] = 0;
    __syncthreads();
    bool is32 = (*flag) != 0;
    for (int i = blockIdx.x * blockDim.x + t; i < E; i += gridDim.x * blockDim.x) {
        int d = is32 ? ei32[E + i] : (int)ei64[E + i];
        atomicAdd(&h[d >> 8], 1);
    }
    __syncthreads();
    if (h[t]) atomicAdd(&bucketCounts[t], h[t]);
}

// Single-block scan of bucket counts -> bucketOffsets / bucketCursor.
__global__ __launch_bounds__(256) void bucket_scan(
    const int* __restrict__ bucketCounts, int* __restrict__ bucketOffsets,
    int* __restrict__ bucketCursor, int* __restrict__ offsets, int NB, int N, int E) {
    __shared__ int sc[256];
    int t = threadIdx.x;
    int c = (t < NB) ? bucketCounts[t] : 0;
    sc[t] = c;
    __syncthreads();
    for (int off = 1; off < 256; off <<= 1) {
        int v = (t >= off) ? sc[t - off] : 0;
        __syncthreads();
        sc[t] += v;
        __syncthreads();
    }
    int excl = sc[t] - c;
    if (t < NB) { bucketOffsets[t] = excl; bucketCursor[t] = excl; }
    if (t == NB - 1) bucketOffsets[NB] = excl + c;
    if (t == 0) offsets[N] = E;
}

// Block-aggregated scatter of (src,dst) pairs into bucket regions.
#define CHUNK 4096
__global__ __launch_bounds__(256) void scatter_pairs(
    const int* __restrict__ ei32, const long long* __restrict__ ei64,
    const int* __restrict__ flag, int* __restrict__ bucketCursor,
    int2* __restrict__ pairs, int E) {
    __shared__ int hist[256], base[256], cur[256];
    int t = threadIdx.x;
    hist[t] = 0; cur[t] = 0;
    __syncthreads();
    int beg = blockIdx.x * CHUNK;
    int end = min(E, beg + CHUNK);
    bool is32 = (*flag) != 0;
    for (int i = beg + t; i < end; i += 256) {
        int d = is32 ? ei32[E + i] : (int)ei64[E + i];
        atomicAdd(&hist[d >> 8], 1);
    }
    __syncthreads();
    if (hist[t] > 0) base[t] = atomicAdd(&bucketCursor[t], hist[t]);
    __syncthreads();
    for (int i = beg + t; i < end; i += 256) {
        int s, d;
        if (is32) { s = ei32[i]; d = ei32[E + i]; }
        else      { s = (int)ei64[i]; d = (int)ei64[E + i]; }
        int b = d >> 8;
        int pos = base[b] + atomicAdd(&cur[b], 1);
        pairs[pos] = make_int2(s, d);
    }
}

// One block per bucket: counting sort by full dst; writes per-node offsets + srcs.
__global__ __launch_bounds__(256) void bucket_sort(
    const int2* __restrict__ pairs, const int* __restrict__ bucketOffsets,
    int* __restrict__ offsets, int* __restrict__ srcs, int N) {
    __shared__ int cnt[256], sc[256], cur[256];
    int b = blockIdx.x, t = threadIdx.x;
    int beg = bucketOffsets[b], end = bucketOffsets[b + 1];
    cnt[t] = 0;
    __syncthreads();
    for (int i = beg + t; i < end; i += 256) atomicAdd(&cnt[pairs[i].y & 255], 1);
    __syncthreads();
    sc[t] = cnt[t];
    __syncthreads();
    for (int off = 1; off < 256; off <<= 1) {
        int v = (t >= off) ? sc[t - off] : 0;
        __syncthreads();
        sc[t] += v;
        __syncthreads();
    }
    int excl = sc[t] - cnt[t];
    int node = (b << 8) + t;
    if (node < N) offsets[node] = beg + excl;
    cur[t] = beg + excl;
    __syncthreads();
    for (int i = beg + t; i < end; i += 256) {
        int2 p = pairs[i];
        int pos = atomicAdd(&cur[p.y & 255], 1);
        srcs[pos] = p.x;
    }
}

// ---------------------------------------------------------------------------
// h = x @ W (+ bias); optionally as_ = h.a_src, ad_ = h.a_dst per node.
__global__ __launch_bounds__(256) void node_transform(
    const float* __restrict__ x, const float* __restrict__ W,
    const float* __restrict__ bias,
    const float* __restrict__ a_src, const float* __restrict__ a_dst,
    float* __restrict__ h, float* __restrict__ as_, float* __restrict__ ad_, int N) {
    __shared__ __align__(16) float Ws[64 * 64];
    __shared__ __align__(16) float xs[32 * 64];
    int tid = threadIdx.x;
    int f = tid & 63;
    int ty = tid >> 6;
    for (int i = tid; i < 64 * 64; i += 256) Ws[i] = W[i];
    int nodeBase = blockIdx.x * 32;
    for (int i = tid; i < 32 * 64; i += 256) {
        int n = nodeBase + (i >> 6);
        xs[i] = (n < N) ? x[(size_t)n * FDIM + (i & 63)] : 0.f;
    }
    __syncthreads();

    float acc[8];
#pragma unroll
    for (int j = 0; j < 8; j++) acc[j] = 0.f;

#pragma unroll
    for (int k = 0; k < 64; k += 4) {
        float w0 = Ws[(k + 0) * 64 + f];
        float w1 = Ws[(k + 1) * 64 + f];
        float w2 = Ws[(k + 2) * 64 + f];
        float w3 = Ws[(k + 3) * 64 + f];
#pragma unroll
        for (int j = 0; j < 8; j++) {
            float4 xv = *(const float4*)&xs[(ty + 4 * j) * 64 + k];
            acc[j] += xv.x * w0 + xv.y * w1 + xv.z * w2 + xv.w * w3;
        }
    }

    float bv = bias ? bias[f] : 0.f;
    float asf = a_src ? a_src[f] : 0.f;
    float adf = a_dst ? a_dst[f] : 0.f;
#pragma unroll
    for (int j = 0; j < 8; j++) {
        int n = nodeBase + ty + 4 * j;
        float hv = acc[j] + bv;
        if (n < N) h[(size_t)n * FDIM + f] = hv;
        if (a_src) {
            float v1 = acc[j] * asf;
            float v2 = acc[j] * adf;
            for (int off = 32; off; off >>= 1) {
                v1 += __shfl_down(v1, off, 64);
                v2 += __shfl_down(v2, off, 64);
            }
            if (f == 0 && n < N) { as_[n] = v1; ad_[n] = v2; }
        }
    }
}

// ---------------------------------------------------------------------------
// One wave per dst node. Feature pass: 4 edges x 16 lanes, float4 h-row loads.
__global__ __launch_bounds__(256) void gat_gather(
    const float* __restrict__ h, const float* __restrict__ as_, const float* __restrict__ ad_,
    const int* __restrict__ offsets, const int* __restrict__ srcs,
    const float* __restrict__ bvec, const float* __restrict__ x0,
    float* __restrict__ xout, int N) {
    int wid = (blockIdx.x * blockDim.x + threadIdx.x) >> 6;
    if (wid >= N) return;
    int lane = threadIdx.x & 63;
    int g = lane >> 4;      // edge slot 0..3
    int q = lane & 15;      // feature quad 0..15
    int beg = offsets[wid], end = offsets[wid + 1];
    float adv = ad_[wid];

    // pass 1: max logit (lane-parallel over edges)
    float m = -INFINITY;
    for (int i = beg + lane; i < end; i += 64) {
        float e = as_[srcs[i]] + adv;
        e = e > 0.f ? e : NEG_SLOPE * e;
        m = fmaxf(m, e);
    }
#pragma unroll
    for (int off = 32; off; off >>= 1) m = fmaxf(m, __shfl_xor(m, off, 64));

    // pass 2: exp-sum + float4 feature accumulation
    float4 acc = {0.f, 0.f, 0.f, 0.f};
    float denom = 0.f;
    const float* hq = h + (q << 2);
    for (int cbeg = beg; cbeg < end; cbeg += 64) {
        int i = cbeg + lane;
        float ex = 0.f;
        int s = 0;
        if (i < end) {
            s = srcs[i];
            float e = as_[s] + adv;
            e = e > 0.f ? e : NEG_SLOPE * e;
            ex = __expf(e - m);
        }
        denom += ex;
        int cnt = min(64, end - cbeg);
        int njj = (cnt + 3) >> 2;
        int jj = 0;
        for (; jj + 2 <= njj; jj += 2) {
            int j0 = (jj << 2) | g, j1 = j0 + 4;
            float ex0 = __shfl(ex, j0, 64), ex1 = __shfl(ex, j1, 64);
            int s0 = __shfl(s, j0, 64), s1 = __shfl(s, j1, 64);
            float4 h0 = *(const float4*)(hq + (size_t)s0 * FDIM);
            float4 h1 = *(const float4*)(hq + (size_t)s1 * FDIM);
            acc.x = fmaf(ex0, h0.x, acc.x); acc.y = fmaf(ex0, h0.y, acc.y);
            acc.z = fmaf(ex0, h0.z, acc.z); acc.w = fmaf(ex0, h0.w, acc.w);
            acc.x = fmaf(ex1, h1.x, acc.x); acc.y = fmaf(ex1, h1.y, acc.y);
            acc.z = fmaf(ex1, h1.z, acc.z); acc.w = fmaf(ex1, h1.w, acc.w);
        }
        if (jj < njj) {
            int j0 = (jj << 2) | g;
            float ex0 = __shfl(ex, j0, 64);
            int s0 = __shfl(s, j0, 64);
            float4 h0 = *(const float4*)(hq + (size_t)s0 * FDIM);
            acc.x = fmaf(ex0, h0.x, acc.x); acc.y = fmaf(ex0, h0.y, acc.y);
            acc.z = fmaf(ex0, h0.z, acc.z); acc.w = fmaf(ex0, h0.w, acc.w);
        }
    }
#pragma unroll
    for (int off = 32; off; off >>= 1) denom += __shfl_xor(denom, off, 64);
#pragma unroll
    for (int off = 16; off <= 32; off <<= 1) {
        acc.x += __shfl_xor(acc.x, off, 64);
        acc.y += __shfl_xor(acc.y, off, 64);
        acc.z += __shfl_xor(acc.z, off, 64);
        acc.w += __shfl_xor(acc.w, off, 64);
    }
    if (g == 0) {
        float inv = denom > 0.f ? 1.f / denom : 0.f;
        float4 b4 = *(const float4*)(bvec + (q << 2));
        float4 xv = *(const float4*)(x0 + (size_t)wid * FDIM + (q << 2));
        float4 o;
        o.x = BETA * (acc.x * inv + b4.x) + (1.f - BETA) * xv.x;
        o.y = BETA * (acc.y * inv + b4.y) + (1.f - BETA) * xv.y;
        o.z = BETA * (acc.z * inv + b4.z) + (1.f - BETA) * xv.z;
        o.w = BETA * (acc.w * inv + b4.w) + (1.f - BETA) * xv.w;
        *(float4*)(xout + (size_t)wid * FDIM + (q << 2)) = o;
    }
}

// ---------------------------------------------------------------------------
extern "C" void kernel_launch(void* const* d_in, const int* in_sizes, int n_in,
                              void* d_out, int out_size, void* d_ws, size_t ws_size,
                              hipStream_t stream) {
    const int N = N_NODES;
    const int E = in_sizes[1] / 2;
    const int NB = (N + 255) >> 8;   // 196 buckets

    const float* x     = (const float*)d_in[0];
    const void*  ei    = d_in[1];
    const float* W     = (const float*)d_in[2];
    const float* a_src = (const float*)d_in[3];
    const float* a_dst = (const float*)d_in[4];
    const float* bvec  = (const float*)d_in[5];
    const float* fc_w  = (const float*)d_in[6];
    const float* fc_b  = (const float*)d_in[7];

    float* out = (float*)d_out;                 // [N, F]
    float* x3  = out + (size_t)N * FDIM;        // [N, F] (second output = h)

    char* p = (char*)d_ws;
    auto alloc = [&](size_t bytes) -> void* {
        void* r = (void*)p;
        p += (bytes + 255) & ~(size_t)255;
        return r;
    };
    int*   flag     = (int*)alloc(256);
    int*   bCounts  = (int*)alloc(256 * 4);
    int*   bOffsets = (int*)alloc(257 * 4);
    int*   bCursor  = (int*)alloc(256 * 4);
    // pairs region is dead after bucket_sort; reuse it as h.
    void*  pairs_h  = alloc((size_t)N * FDIM * 4 > (size_t)E * 8 ? (size_t)N * FDIM * 4
                                                                 : (size_t)E * 8);
    int*   srcs     = (int*)alloc((size_t)E * 4);
    int*   offsets  = (int*)alloc((size_t)(N + 1) * 4);
    float* as_      = (float*)alloc((size_t)N * 4);
    float* ad_      = (float*)alloc((size_t)N * 4);
    float* xbuf     = (float*)alloc((size_t)N * FDIM * 4);

    int2*  pairs = (int2*)pairs_h;
    float* h     = (float*)pairs_h;

    hipMemsetAsync(flag, 0, 4, stream);
    hipMemsetAsync(bCounts, 0, 256 * 4, stream);

    const int nCheck = 65536;
    detect_kernel<<<nCheck / 256, 256, 0, stream>>>((const unsigned int*)ei, flag, nCheck);

    hist_kernel<<<512, 256, 0, stream>>>((const int*)ei, (const long long*)ei, flag, bCounts, E);
    bucket_scan<<<1, 256, 0, stream>>>(bCounts, bOffsets, bCursor, offsets, NB, N, E);
    scatter_pairs<<<(E + CHUNK - 1) / CHUNK, 256, 0, stream>>>(
        (const int*)ei, (const long long*)ei, flag, bCursor, pairs, E);
    bucket_sort<<<NB, 256, 0, stream>>>(pairs, bOffsets, offsets, srcs, N);

    int tgrid = (N + 31) / 32;
    int ggrid = (N * 64 + 255) / 256;

    // layer 1
    node_transform<<<tgrid, 256, 0, stream>>>(x, W, nullptr, a_src, a_dst, h, as_, ad_, N);
    gat_gather<<<ggrid, 256, 0, stream>>>(h, as_, ad_, offsets, srcs, bvec, x, xbuf, N);
    // layer 2
    node_transform<<<tgrid, 256, 0, stream>>>(xbuf, W, nullptr, a_src, a_dst, h, as_, ad_, N);
    gat_gather<<<ggrid, 256, 0, stream>>>(h, as_, ad_, offsets, srcs, bvec, x, xbuf, N);
    // layer 3
    node_transform<<<tgrid, 256, 0, stream>>>(xbuf, W, nullptr, a_src, a_dst, h, as_, ad_, N);
    gat_gather<<<ggrid, 256, 0, stream>>>(h, as_, ad_, offsets, srcs, bvec, x, x3, N);
    // final fc: out = x3 @ fc_w + fc_b
    node_transform<<<tgrid, 256, 0, stream>>>(x3, fc_w, fc_b, nullptr, nullptr, out, nullptr, nullptr, N);
}

// Round 3
// 417.687 us; speedup vs baseline: 2.5228x; 1.6014x over previous
//
#include <hip/hip_runtime.h>
#include <hip/hip_bf16.h>
#include <math.h>

#define N_NODES 50000
#define FDIM 64
#define BETA 0.5f
#define NEG_SLOPE 0.2f

// ---------------------------------------------------------------------------
// Detect whether edge_index is int64 (high dwords all zero) or int32.
// flag==1 -> int32 data, flag==0 -> int64 data.
__global__ void detect_kernel(const unsigned int* __restrict__ ei, int* flag, int nCheck) {
    int i = blockIdx.x * blockDim.x + threadIdx.x;
    if (i < nCheck) {
        if (ei[2 * i + 1] != 0u) atomicOr(flag, 1);
    }
}

// LDS-aggregated histogram of dst buckets (bucket = dst>>8).
__global__ __launch_bounds__(256) void hist_kernel(
    const int* __restrict__ ei32, const long long* __restrict__ ei64,
    const int* __restrict__ flag, int* __restrict__ bucketCounts, int E) {
    __shared__ int h[256];
    int t = threadIdx.x;
    h[t] = 0;
    __syncthreads();
    bool is32 = (*flag) != 0;
    for (int i = blockIdx.x * blockDim.x + t; i < E; i += gridDim.x * blockDim.x) {
        int d = is32 ? ei32[E + i] : (int)ei64[E + i];
        atomicAdd(&h[d >> 8], 1);
    }
    __syncthreads();
    if (h[t]) atomicAdd(&bucketCounts[t], h[t]);
}

// Single-block scan of bucket counts -> bucketOffsets / bucketCursor.
__global__ __launch_bounds__(256) void bucket_scan(
    const int* __restrict__ bucketCounts, int* __restrict__ bucketOffsets,
    int* __restrict__ bucketCursor, int* __restrict__ offsets, int NB, int N, int E) {
    __shared__ int sc[256];
    int t = threadIdx.x;
    int c = (t < NB) ? bucketCounts[t] : 0;
    sc[t] = c;
    __syncthreads();
    for (int off = 1; off < 256; off <<= 1) {
        int v = (t >= off) ? sc[t - off] : 0;
        __syncthreads();
        sc[t] += v;
        __syncthreads();
    }
    int excl = sc[t] - c;
    if (t < NB) { bucketOffsets[t] = excl; bucketCursor[t] = excl; }
    if (t == NB - 1) bucketOffsets[NB] = excl + c;
    if (t == 0) offsets[N] = E;
}

// Block-aggregated scatter of (src,dst) pairs into bucket regions.
#define CHUNK 4096
__global__ __launch_bounds__(256) void scatter_pairs(
    const int* __restrict__ ei32, const long long* __restrict__ ei64,
    const int* __restrict__ flag, int* __restrict__ bucketCursor,
    int2* __restrict__ pairs, int E) {
    __shared__ int hist[256], base[256], cur[256];
    int t = threadIdx.x;
    hist[t] = 0; cur[t] = 0;
    __syncthreads();
    int beg = blockIdx.x * CHUNK;
    int end = min(E, beg + CHUNK);
    bool is32 = (*flag) != 0;
    for (int i = beg + t; i < end; i += 256) {
        int d = is32 ? ei32[E + i] : (int)ei64[E + i];
        atomicAdd(&hist[d >> 8], 1);
    }
    __syncthreads();
    if (hist[t] > 0) base[t] = atomicAdd(&bucketCursor[t], hist[t]);
    __syncthreads();
    for (int i = beg + t; i < end; i += 256) {
        int s, d;
        if (is32) { s = ei32[i]; d = ei32[E + i]; }
        else      { s = (int)ei64[i]; d = (int)ei64[E + i]; }
        int b = d >> 8;
        int pos = base[b] + atomicAdd(&cur[b], 1);
        pairs[pos] = make_int2(s, d);
    }
}

// One block per bucket: counting sort by full dst; writes per-node offsets + srcs.
__global__ __launch_bounds__(256) void bucket_sort(
    const int2* __restrict__ pairs, const int* __restrict__ bucketOffsets,
    int* __restrict__ offsets, int* __restrict__ srcs, int N) {
    __shared__ int cnt[256], sc[256], cur[256];
    int b = blockIdx.x, t = threadIdx.x;
    int beg = bucketOffsets[b], end = bucketOffsets[b + 1];
    cnt[t] = 0;
    __syncthreads();
    for (int i = beg + t; i < end; i += 256) atomicAdd(&cnt[pairs[i].y & 255], 1);
    __syncthreads();
    sc[t] = cnt[t];
    __syncthreads();
    for (int off = 1; off < 256; off <<= 1) {
        int v = (t >= off) ? sc[t - off] : 0;
        __syncthreads();
        sc[t] += v;
        __syncthreads();
    }
    int excl = sc[t] - cnt[t];
    int node = (b << 8) + t;
    if (node < N) offsets[node] = beg + excl;
    cur[t] = beg + excl;
    __syncthreads();
    for (int i = beg + t; i < end; i += 256) {
        int2 p = pairs[i];
        int pos = atomicAdd(&cur[p.y & 255], 1);
        srcs[pos] = p.x;
    }
}

// ---------------------------------------------------------------------------
// h = x @ W (+ bias); optionally as_ = h.a_src, ad_ = h.a_dst per node.
// 16 nodes/block, 4 nodes/thread, k-loop NOT unrolled (spill control).
// xs reads are wave-uniform (LDS broadcast); Ws reads are 2-way (free).
__global__ __launch_bounds__(256, 4) void node_transform(
    const float* __restrict__ x, const float* __restrict__ W,
    const float* __restrict__ bias,
    const float* __restrict__ a_src, const float* __restrict__ a_dst,
    float* __restrict__ h, float* __restrict__ as_, float* __restrict__ ad_, int N) {
    __shared__ __align__(16) float Ws[64 * 64];   // 16 KB
    __shared__ __align__(16) float xs[16 * 64];   // 4 KB
    int tid = threadIdx.x;
    int f = tid & 63;
    int ty = tid >> 6;          // 0..3
    // stage W (4096 floats) as float4
    {
        const float4* W4 = (const float4*)W;
        float4* Ws4 = (float4*)Ws;
        for (int i = tid; i < 1024; i += 256) Ws4[i] = W4[i];
    }
    int nodeBase = blockIdx.x * 16;
    // stage 16 node rows (1024 floats = 256 float4), thread i -> float4 i
    {
        int n = nodeBase + (tid >> 4);
        const float4* xrow = (const float4*)(x + (size_t)n * FDIM);
        float4 v = (n < N) ? xrow[tid & 15] : make_float4(0.f, 0.f, 0.f, 0.f);
        ((float4*)xs)[tid] = v;
    }
    __syncthreads();

    float acc[4] = {0.f, 0.f, 0.f, 0.f};

#pragma unroll 1
    for (int k = 0; k < 64; k += 4) {
        float w0 = Ws[(k + 0) * 64 + f];
        float w1 = Ws[(k + 1) * 64 + f];
        float w2 = Ws[(k + 2) * 64 + f];
        float w3 = Ws[(k + 3) * 64 + f];
#pragma unroll
        for (int j = 0; j < 4; j++) {
            float4 xv = *(const float4*)&xs[(ty * 4 + j) * 64 + k];
            acc[j] = fmaf(xv.x, w0, acc[j]);
            acc[j] = fmaf(xv.y, w1, acc[j]);
            acc[j] = fmaf(xv.z, w2, acc[j]);
            acc[j] = fmaf(xv.w, w3, acc[j]);
        }
    }

    float bv = bias ? bias[f] : 0.f;
    float asf = a_src ? a_src[f] : 0.f;
    float adf = a_dst ? a_dst[f] : 0.f;
#pragma unroll
    for (int j = 0; j < 4; j++) {
        int n = nodeBase + ty * 4 + j;
        if (n < N) h[(size_t)n * FDIM + f] = acc[j] + bv;
        if (a_src) {
            float v1 = acc[j] * asf;
            float v2 = acc[j] * adf;
#pragma unroll
            for (int off = 32; off; off >>= 1) {
                v1 += __shfl_down(v1, off, 64);
                v2 += __shfl_down(v2, off, 64);
            }
            if (f == 0 && n < N) { as_[n] = v1; ad_[n] = v2; }
        }
    }
}

// ---------------------------------------------------------------------------
// One wave per dst node. Feature pass: 4 edges x 16 lanes, float4 h-row loads.
__global__ __launch_bounds__(256) void gat_gather(
    const float* __restrict__ h, const float* __restrict__ as_, const float* __restrict__ ad_,
    const int* __restrict__ offsets, const int* __restrict__ srcs,
    const float* __restrict__ bvec, const float* __restrict__ x0,
    float* __restrict__ xout, int N) {
    int wid = (blockIdx.x * blockDim.x + threadIdx.x) >> 6;
    if (wid >= N) return;
    int lane = threadIdx.x & 63;
    int g = lane >> 4;      // edge slot 0..3
    int q = lane & 15;      // feature quad 0..15
    int beg = offsets[wid], end = offsets[wid + 1];
    float adv = ad_[wid];

    // pass 1: max logit (lane-parallel over edges)
    float m = -INFINITY;
    for (int i = beg + lane; i < end; i += 64) {
        float e = as_[srcs[i]] + adv;
        e = e > 0.f ? e : NEG_SLOPE * e;
        m = fmaxf(m, e);
    }
#pragma unroll
    for (int off = 32; off; off >>= 1) m = fmaxf(m, __shfl_xor(m, off, 64));

    // pass 2: exp-sum + float4 feature accumulation
    float4 acc = {0.f, 0.f, 0.f, 0.f};
    float denom = 0.f;
    const float* hq = h + (q << 2);
    for (int cbeg = beg; cbeg < end; cbeg += 64) {
        int i = cbeg + lane;
        float ex = 0.f;
        int s = 0;
        if (i < end) {
            s = srcs[i];
            float e = as_[s] + adv;
            e = e > 0.f ? e : NEG_SLOPE * e;
            ex = __expf(e - m);
        }
        denom += ex;
        int cnt = min(64, end - cbeg);
        int njj = (cnt + 3) >> 2;
        int jj = 0;
        for (; jj + 2 <= njj; jj += 2) {
            int j0 = (jj << 2) | g, j1 = j0 + 4;
            float ex0 = __shfl(ex, j0, 64), ex1 = __shfl(ex, j1, 64);
            int s0 = __shfl(s, j0, 64), s1 = __shfl(s, j1, 64);
            float4 h0 = *(const float4*)(hq + (size_t)s0 * FDIM);
            float4 h1 = *(const float4*)(hq + (size_t)s1 * FDIM);
            acc.x = fmaf(ex0, h0.x, acc.x); acc.y = fmaf(ex0, h0.y, acc.y);
            acc.z = fmaf(ex0, h0.z, acc.z); acc.w = fmaf(ex0, h0.w, acc.w);
            acc.x = fmaf(ex1, h1.x, acc.x); acc.y = fmaf(ex1, h1.y, acc.y);
            acc.z = fmaf(ex1, h1.z, acc.z); acc.w = fmaf(ex1, h1.w, acc.w);
        }
        if (jj < njj) {
            int j0 = (jj << 2) | g;
            float ex0 = __shfl(ex, j0, 64);
            int s0 = __shfl(s, j0, 64);
            float4 h0 = *(const float4*)(hq + (size_t)s0 * FDIM);
            acc.x = fmaf(ex0, h0.x, acc.x); acc.y = fmaf(ex0, h0.y, acc.y);
            acc.z = fmaf(ex0, h0.z, acc.z); acc.w = fmaf(ex0, h0.w, acc.w);
        }
    }
#pragma unroll
    for (int off = 32; off; off >>= 1) denom += __shfl_xor(denom, off, 64);
#pragma unroll
    for (int off = 16; off <= 32; off <<= 1) {
        acc.x += __shfl_xor(acc.x, off, 64);
        acc.y += __shfl_xor(acc.y, off, 64);
        acc.z += __shfl_xor(acc.z, off, 64);
        acc.w += __shfl_xor(acc.w, off, 64);
    }
    if (g == 0) {
        float inv = denom > 0.f ? 1.f / denom : 0.f;
        float4 b4 = *(const float4*)(bvec + (q << 2));
        float4 xv = *(const float4*)(x0 + (size_t)wid * FDIM + (q << 2));
        float4 o;
        o.x = BETA * (acc.x * inv + b4.x) + (1.f - BETA) * xv.x;
        o.y = BETA * (acc.y * inv + b4.y) + (1.f - BETA) * xv.y;
        o.z = BETA * (acc.z * inv + b4.z) + (1.f - BETA) * xv.z;
        o.w = BETA * (acc.w * inv + b4.w) + (1.f - BETA) * xv.w;
        *(float4*)(xout + (size_t)wid * FDIM + (q << 2)) = o;
    }
}

// ---------------------------------------------------------------------------
extern "C" void kernel_launch(void* const* d_in, const int* in_sizes, int n_in,
                              void* d_out, int out_size, void* d_ws, size_t ws_size,
                              hipStream_t stream) {
    const int N = N_NODES;
    const int E = in_sizes[1] / 2;
    const int NB = (N + 255) >> 8;   // 196 buckets

    const float* x     = (const float*)d_in[0];
    const void*  ei    = d_in[1];
    const float* W     = (const float*)d_in[2];
    const float* a_src = (const float*)d_in[3];
    const float* a_dst = (const float*)d_in[4];
    const float* bvec  = (const float*)d_in[5];
    const float* fc_w  = (const float*)d_in[6];
    const float* fc_b  = (const float*)d_in[7];

    float* out = (float*)d_out;                 // [N, F]
    float* x3  = out + (size_t)N * FDIM;        // [N, F] (second output = h)

    char* p = (char*)d_ws;
    auto alloc = [&](size_t bytes) -> void* {
        void* r = (void*)p;
        p += (bytes + 255) & ~(size_t)255;
        return r;
    };
    int*   flag     = (int*)alloc(256);
    int*   bCounts  = (int*)alloc(256 * 4);
    int*   bOffsets = (int*)alloc(257 * 4);
    int*   bCursor  = (int*)alloc(256 * 4);
    // pairs region is dead after bucket_sort; reuse it as h.
    void*  pairs_h  = alloc((size_t)N * FDIM * 4 > (size_t)E * 8 ? (size_t)N * FDIM * 4
                                                                 : (size_t)E * 8);
    int*   srcs     = (int*)alloc((size_t)E * 4);
    int*   offsets  = (int*)alloc((size_t)(N + 1) * 4);
    float* as_      = (float*)alloc((size_t)N * 4);
    float* ad_      = (float*)alloc((size_t)N * 4);
    float* xbuf     = (float*)alloc((size_t)N * FDIM * 4);

    int2*  pairs = (int2*)pairs_h;
    float* h     = (float*)pairs_h;

    hipMemsetAsync(flag, 0, 4, stream);
    hipMemsetAsync(bCounts, 0, 256 * 4, stream);

    const int nCheck = 65536;
    detect_kernel<<<nCheck / 256, 256, 0, stream>>>((const unsigned int*)ei, flag, nCheck);

    hist_kernel<<<512, 256, 0, stream>>>((const int*)ei, (const long long*)ei, flag, bCounts, E);
    bucket_scan<<<1, 256, 0, stream>>>(bCounts, bOffsets, bCursor, offsets, NB, N, E);
    scatter_pairs<<<(E + CHUNK - 1) / CHUNK, 256, 0, stream>>>(
        (const int*)ei, (const long long*)ei, flag, bCursor, pairs, E);
    bucket_sort<<<NB, 256, 0, stream>>>(pairs, bOffsets, offsets, srcs, N);

    int tgrid = (N + 15) / 16;
    int ggrid = (N * 64 + 255) / 256;

    // layer 1
    node_transform<<<tgrid, 256, 0, stream>>>(x, W, nullptr, a_src, a_dst, h, as_, ad_, N);
    gat_gather<<<ggrid, 256, 0, stream>>>(h, as_, ad_, offsets, srcs, bvec, x, xbuf, N);
    // layer 2
    node_transform<<<tgrid, 256, 0, stream>>>(xbuf, W, nullptr, a_src, a_dst, h, as_, ad_, N);
    gat_gather<<<ggrid, 256, 0, stream>>>(h, as_, ad_, offsets, srcs, bvec, x, xbuf, N);
    // layer 3
    node_transform<<<tgrid, 256, 0, stream>>>(xbuf, W, nullptr, a_src, a_dst, h, as_, ad_, N);
    gat_gather<<<ggrid, 256, 0, stream>>>(h, as_, ad_, offsets, srcs, bvec, x, x3, N);
    // final fc: out = x3 @ fc_w + fc_b
    node_transform<<<tgrid, 256, 0, stream>>>(x3, fc_w, fc_b, nullptr, nullptr, out, nullptr, nullptr, N);
}

// Round 5
// 342.739 us; speedup vs baseline: 3.0745x; 1.2187x over previous
//
#include <hip/hip_runtime.h>
#include <hip/hip_bf16.h>
#include <math.h>

#define N_NODES 50000
#define FDIM 64
#define BETA 0.5f
#define NEG_SLOPE 0.2f

__device__ __forceinline__ unsigned short f2bf(float f) {
    unsigned u = __float_as_uint(f);
    unsigned r = (u + 0x7FFFu + ((u >> 16) & 1u)) >> 16;
    return (unsigned short)r;
}
__device__ __forceinline__ float bf2f(unsigned short s) {
    return __uint_as_float((unsigned)s << 16);
}

// ---------------------------------------------------------------------------
// Detect whether edge_index is int64 (high dwords all zero) or int32.
__global__ void detect_kernel(const unsigned int* __restrict__ ei, int* flag, int nCheck) {
    int i = blockIdx.x * blockDim.x + threadIdx.x;
    if (i < nCheck) {
        if (ei[2 * i + 1] != 0u) atomicOr(flag, 1);
    }
}

// LDS-aggregated histogram of dst buckets (bucket = dst>>8).
__global__ __launch_bounds__(256) void hist_kernel(
    const int* __restrict__ ei32, const long long* __restrict__ ei64,
    const int* __restrict__ flag, int* __restrict__ bucketCounts, int E) {
    __shared__ int h[256];
    int t = threadIdx.x;
    h[t] = 0;
    __syncthreads();
    bool is32 = (*flag) != 0;
    for (int i = blockIdx.x * blockDim.x + t; i < E; i += gridDim.x * blockDim.x) {
        int d = is32 ? ei32[E + i] : (int)ei64[E + i];
        atomicAdd(&h[d >> 8], 1);
    }
    __syncthreads();
    if (h[t]) atomicAdd(&bucketCounts[t], h[t]);
}

// Single-block scan of bucket counts -> bucketOffsets / bucketCursor.
__global__ __launch_bounds__(256) void bucket_scan(
    const int* __restrict__ bucketCounts, int* __restrict__ bucketOffsets,
    int* __restrict__ bucketCursor, int* __restrict__ offsets, int NB, int N, int E) {
    __shared__ int sc[256];
    int t = threadIdx.x;
    int c = (t < NB) ? bucketCounts[t] : 0;
    sc[t] = c;
    __syncthreads();
    for (int off = 1; off < 256; off <<= 1) {
        int v = (t >= off) ? sc[t - off] : 0;
        __syncthreads();
        sc[t] += v;
        __syncthreads();
    }
    int excl = sc[t] - c;
    if (t < NB) { bucketOffsets[t] = excl; bucketCursor[t] = excl; }
    if (t == NB - 1) bucketOffsets[NB] = excl + c;
    if (t == 0) offsets[N] = E;
}

// Block-aggregated scatter of packed (src | dlow<<16) into bucket regions.
#define CHUNK 4096
__global__ __launch_bounds__(256) void scatter_pairs(
    const int* __restrict__ ei32, const long long* __restrict__ ei64,
    const int* __restrict__ flag, int* __restrict__ bucketCursor,
    unsigned int* __restrict__ pairs, int E) {
    __shared__ int hist[256], base[256], cur[256];
    int t = threadIdx.x;
    hist[t] = 0; cur[t] = 0;
    __syncthreads();
    int beg = blockIdx.x * CHUNK;
    int end = min(E, beg + CHUNK);
    bool is32 = (*flag) != 0;
    for (int i = beg + t; i < end; i += 256) {
        int d = is32 ? ei32[E + i] : (int)ei64[E + i];
        atomicAdd(&hist[d >> 8], 1);
    }
    __syncthreads();
    if (hist[t] > 0) base[t] = atomicAdd(&bucketCursor[t], hist[t]);
    __syncthreads();
    for (int i = beg + t; i < end; i += 256) {
        int s, d;
        if (is32) { s = ei32[i]; d = ei32[E + i]; }
        else      { s = (int)ei64[i]; d = (int)ei64[E + i]; }
        int b = d >> 8;
        int pos = base[b] + atomicAdd(&cur[b], 1);
        pairs[pos] = (unsigned int)s | ((unsigned int)(d & 255) << 16);
    }
}

// One block per bucket: counting sort by full dst; writes per-node offsets + srcs.
__global__ __launch_bounds__(256) void bucket_sort(
    const unsigned int* __restrict__ pairs, const int* __restrict__ bucketOffsets,
    int* __restrict__ offsets, int* __restrict__ srcs, int N) {
    __shared__ int cnt[256], sc[256], cur[256];
    int b = blockIdx.x, t = threadIdx.x;
    int beg = bucketOffsets[b], end = bucketOffsets[b + 1];
    cnt[t] = 0;
    __syncthreads();
    for (int i = beg + t; i < end; i += 256) atomicAdd(&cnt[(pairs[i] >> 16) & 255u], 1);
    __syncthreads();
    sc[t] = cnt[t];
    __syncthreads();
    for (int off = 1; off < 256; off <<= 1) {
        int v = (t >= off) ? sc[t - off] : 0;
        __syncthreads();
        sc[t] += v;
        __syncthreads();
    }
    int excl = sc[t] - cnt[t];
    int node = (b << 8) + t;
    if (node < N) offsets[node] = beg + excl;
    cur[t] = beg + excl;
    __syncthreads();
    for (int i = beg + t; i < end; i += 256) {
        unsigned int p = pairs[i];
        int pos = atomicAdd(&cur[(p >> 16) & 255u], 1);
        srcs[pos] = (int)(p & 0xFFFFu);
    }
}

// ---------------------------------------------------------------------------
// h = x @ W (+ bias); h written fp32 (hf) or bf16 (hb). Optional as_/ad_.
// 16 nodes/block, 4 nodes/thread, k-loop NOT unrolled (spill control).
__global__ __launch_bounds__(256, 4) void node_transform(
    const float* __restrict__ x, const float* __restrict__ W,
    const float* __restrict__ bias,
    const float* __restrict__ a_src, const float* __restrict__ a_dst,
    float* __restrict__ hf, unsigned short* __restrict__ hb,
    float* __restrict__ as_, float* __restrict__ ad_, int N) {
    __shared__ __align__(16) float Ws[64 * 64];   // 16 KB
    __shared__ __align__(16) float xs[16 * 64];   // 4 KB
    int tid = threadIdx.x;
    int f = tid & 63;
    int ty = tid >> 6;          // 0..3
    {
        const float4* W4 = (const float4*)W;
        float4* Ws4 = (float4*)Ws;
        for (int i = tid; i < 1024; i += 256) Ws4[i] = W4[i];
    }
    int nodeBase = blockIdx.x * 16;
    {
        int n = nodeBase + (tid >> 4);
        const float4* xrow = (const float4*)(x + (size_t)n * FDIM);
        float4 v = (n < N) ? xrow[tid & 15] : make_float4(0.f, 0.f, 0.f, 0.f);
        ((float4*)xs)[tid] = v;
    }
    __syncthreads();

    float acc[4] = {0.f, 0.f, 0.f, 0.f};

#pragma unroll 1
    for (int k = 0; k < 64; k += 4) {
        float w0 = Ws[(k + 0) * 64 + f];
        float w1 = Ws[(k + 1) * 64 + f];
        float w2 = Ws[(k + 2) * 64 + f];
        float w3 = Ws[(k + 3) * 64 + f];
#pragma unroll
        for (int j = 0; j < 4; j++) {
            float4 xv = *(const float4*)&xs[(ty * 4 + j) * 64 + k];
            acc[j] = fmaf(xv.x, w0, acc[j]);
            acc[j] = fmaf(xv.y, w1, acc[j]);
            acc[j] = fmaf(xv.z, w2, acc[j]);
            acc[j] = fmaf(xv.w, w3, acc[j]);
        }
    }

    float bv = bias ? bias[f] : 0.f;
    float asf = a_src ? a_src[f] : 0.f;
    float adf = a_dst ? a_dst[f] : 0.f;
#pragma unroll
    for (int j = 0; j < 4; j++) {
        int n = nodeBase + ty * 4 + j;
        float hv = acc[j] + bv;
        if (n < N) {
            if (hf) hf[(size_t)n * FDIM + f] = hv;
            if (hb) hb[(size_t)n * FDIM + f] = f2bf(hv);
        }
        if (a_src) {
            float v1 = acc[j] * asf;
            float v2 = acc[j] * adf;
#pragma unroll
            for (int off = 32; off; off >>= 1) {
                v1 += __shfl_down(v1, off, 64);
                v2 += __shfl_down(v2, off, 64);
            }
            if (f == 0 && n < N) { as_[n] = v1; ad_[n] = v2; }
        }
    }
}

// ---------------------------------------------------------------------------
// One wave per dst node, single pass (no max subtraction: logits bounded,
// fp32 exp safe to |e|<88). 4 edges x 16 lanes, bf16 ushort4 h-row loads,
// 4-deep unroll for memory-level parallelism.
__global__ __launch_bounds__(256) void gat_gather(
    const unsigned short* __restrict__ hb,
    const float* __restrict__ as_, const float* __restrict__ ad_,
    const int* __restrict__ offsets, const int* __restrict__ srcs,
    const float* __restrict__ bvec, const float* __restrict__ x0,
    float* __restrict__ xout, int N) {
    int wid = (blockIdx.x * blockDim.x + threadIdx.x) >> 6;
    if (wid >= N) return;
    int lane = threadIdx.x & 63;
    int g = lane >> 4;      // edge slot 0..3
    int q = lane & 15;      // feature quad 0..15
    int beg = offsets[wid], end = offsets[wid + 1];
    float adv = ad_[wid];

    float4 acc = {0.f, 0.f, 0.f, 0.f};
    float denom = 0.f;
    const unsigned short* hq = hb + (q << 2);

#define SLOT(J)                                                              \
    {                                                                        \
        int j_ = (J);                                                        \
        float exj = __shfl(ex, j_, 64);                                      \
        int sj = __shfl(s, j_, 64);                                          \
        ushort4 hv = *(const ushort4*)(hq + (size_t)sj * FDIM);              \
        acc.x = fmaf(exj, bf2f(hv.x), acc.x);                                \
        acc.y = fmaf(exj, bf2f(hv.y), acc.y);                                \
        acc.z = fmaf(exj, bf2f(hv.z), acc.z);                                \
        acc.w = fmaf(exj, bf2f(hv.w), acc.w);                                \
    }

    for (int cbeg = beg; cbeg < end; cbeg += 64) {
        int i = cbeg + lane;
        float ex = 0.f;
        int s = 0;
        if (i < end) {
            s = srcs[i];
            float e = as_[s] + adv;
            e = e > 0.f ? e : NEG_SLOPE * e;
            ex = __expf(e);
        }
        denom += ex;
        int cnt = min(64, end - cbeg);
        int njj = (cnt + 3) >> 2;
        int jj = 0;
        for (; jj + 4 <= njj; jj += 4) {
            int j0 = (jj << 2) | g;
            SLOT(j0); SLOT(j0 + 4); SLOT(j0 + 8); SLOT(j0 + 12);
        }
        for (; jj < njj; jj++) {
            SLOT((jj << 2) | g);
        }
    }
#undef SLOT

#pragma unroll
    for (int off = 32; off; off >>= 1) denom += __shfl_xor(denom, off, 64);
#pragma unroll
    for (int off = 16; off <= 32; off <<= 1) {
        acc.x += __shfl_xor(acc.x, off, 64);
        acc.y += __shfl_xor(acc.y, off, 64);
        acc.z += __shfl_xor(acc.z, off, 64);
        acc.w += __shfl_xor(acc.w, off, 64);
    }
    if (g == 0) {
        float inv = denom > 0.f ? 1.f / denom : 0.f;
        float4 b4 = *(const float4*)(bvec + (q << 2));
        float4 xv = *(const float4*)(x0 + (size_t)wid * FDIM + (q << 2));
        float4 o;
        o.x = BETA * (acc.x * inv + b4.x) + (1.f - BETA) * xv.x;
        o.y = BETA * (acc.y * inv + b4.y) + (1.f - BETA) * xv.y;
        o.z = BETA * (acc.z * inv + b4.z) + (1.f - BETA) * xv.z;
        o.w = BETA * (acc.w * inv + b4.w) + (1.f - BETA) * xv.w;
        *(float4*)(xout + (size_t)wid * FDIM + (q << 2)) = o;
    }
}

// ---------------------------------------------------------------------------
extern "C" void kernel_launch(void* const* d_in, const int* in_sizes, int n_in,
                              void* d_out, int out_size, void* d_ws, size_t ws_size,
                              hipStream_t stream) {
    const int N = N_NODES;
    const int E = in_sizes[1] / 2;
    const int NB = (N + 255) >> 8;   // 196 buckets

    const float* x     = (const float*)d_in[0];
    const void*  ei    = d_in[1];
    const float* W     = (const float*)d_in[2];
    const float* a_src = (const float*)d_in[3];
    const float* a_dst = (const float*)d_in[4];
    const float* bvec  = (const float*)d_in[5];
    const float* fc_w  = (const float*)d_in[6];
    const float* fc_b  = (const float*)d_in[7];

    float* out = (float*)d_out;                 // [N, F]
    float* x3  = out + (size_t)N * FDIM;        // [N, F] (second output = h)

    char* p = (char*)d_ws;
    auto alloc = [&](size_t bytes) -> void* {
        void* r = (void*)p;
        p += (bytes + 255) & ~(size_t)255;
        return r;
    };
    int*            flag     = (int*)alloc(256);
    int*            bCounts  = (int*)alloc(256 * 4);
    int*            bOffsets = (int*)alloc(257 * 4);
    int*            bCursor  = (int*)alloc(256 * 4);
    unsigned int*   pairs    = (unsigned int*)alloc((size_t)E * 4);
    int*            srcs     = (int*)alloc((size_t)E * 4);
    int*            offsets  = (int*)alloc((size_t)(N + 1) * 4);
    float*          as_      = (float*)alloc((size_t)N * 4);
    float*          ad_      = (float*)alloc((size_t)N * 4);
    unsigned short* hbuf     = (unsigned short*)alloc((size_t)N * FDIM * 2);
    float*          xbuf     = (float*)alloc((size_t)N * FDIM * 4);

    hipMemsetAsync(flag, 0, 4, stream);
    hipMemsetAsync(bCounts, 0, 256 * 4, stream);

    const int nCheck = 65536;
    detect_kernel<<<nCheck / 256, 256, 0, stream>>>((const unsigned int*)ei, flag, nCheck);

    hist_kernel<<<512, 256, 0, stream>>>((const int*)ei, (const long long*)ei, flag, bCounts, E);
    bucket_scan<<<1, 256, 0, stream>>>(bCounts, bOffsets, bCursor, offsets, NB, N, E);
    scatter_pairs<<<(E + CHUNK - 1) / CHUNK, 256, 0, stream>>>(
        (const int*)ei, (const long long*)ei, flag, bCursor, pairs, E);
    bucket_sort<<<NB, 256, 0, stream>>>(pairs, bOffsets, offsets, srcs, N);

    int tgrid = (N + 15) / 16;
    int ggrid = (N * 64 + 255) / 256;

    // layer 1
    node_transform<<<tgrid, 256, 0, stream>>>(x, W, nullptr, a_src, a_dst, nullptr, hbuf, as_, ad_, N);
    gat_gather<<<ggrid, 256, 0, stream>>>(hbuf, as_, ad_, offsets, srcs, bvec, x, xbuf, N);
    // layer 2
    node_transform<<<tgrid, 256, 0, stream>>>(xbuf, W, nullptr, a_src, a_dst, nullptr, hbuf, as_, ad_, N);
    gat_gather<<<ggrid, 256, 0, stream>>>(hbuf, as_, ad_, offsets, srcs, bvec, x, xbuf, N);
    // layer 3
    node_transform<<<tgrid, 256, 0, stream>>>(xbuf, W, nullptr, a_src, a_dst, nullptr, hbuf, as_, ad_, N);
    gat_gather<<<ggrid, 256, 0, stream>>>(hbuf, as_, ad_, offsets, srcs, bvec, x, x3, N);
    // final fc: out = x3 @ fc_w + fc_b
    node_transform<<<tgrid, 256, 0, stream>>>(x3, fc_w, fc_b, nullptr, nullptr,
                                              out, nullptr, nullptr, nullptr, N);
}

// Round 6
// 295.179 us; speedup vs baseline: 3.5698x; 1.1611x over previous
//
#include <hip/hip_runtime.h>
#include <hip/hip_bf16.h>
#include <math.h>

#define N_NODES 50000
#define FDIM 64
#define BETA 0.5f
#define NEG_SLOPE 0.2f

typedef __attribute__((ext_vector_type(8))) short bf16x8;
typedef __attribute__((ext_vector_type(4))) float f32x4;

__device__ __forceinline__ unsigned short f2bf(float f) {
    unsigned u = __float_as_uint(f);
    unsigned r = (u + 0x7FFFu + ((u >> 16) & 1u)) >> 16;
    return (unsigned short)r;
}
__device__ __forceinline__ float bf2f(unsigned short s) {
    return __uint_as_float((unsigned)s << 16);
}

// ---------------------------------------------------------------------------
// Detect whether edge_index is int64 (high dwords all zero) or int32.
__global__ void detect_kernel(const unsigned int* __restrict__ ei, int* flag, int nCheck) {
    int i = blockIdx.x * blockDim.x + threadIdx.x;
    if (i < nCheck) {
        if (ei[2 * i + 1] != 0u) atomicOr(flag, 1);
    }
}

// LDS-aggregated histogram of dst buckets (bucket = dst>>8).
__global__ __launch_bounds__(256) void hist_kernel(
    const int* __restrict__ ei32, const long long* __restrict__ ei64,
    const int* __restrict__ flag, int* __restrict__ bucketCounts, int E) {
    __shared__ int h[256];
    int t = threadIdx.x;
    h[t] = 0;
    __syncthreads();
    bool is32 = (*flag) != 0;
    for (int i = blockIdx.x * blockDim.x + t; i < E; i += gridDim.x * blockDim.x) {
        int d = is32 ? ei32[E + i] : (int)ei64[E + i];
        atomicAdd(&h[d >> 8], 1);
    }
    __syncthreads();
    if (h[t]) atomicAdd(&bucketCounts[t], h[t]);
}

// Single-block scan of bucket counts -> bucketOffsets / bucketCursor.
__global__ __launch_bounds__(256) void bucket_scan(
    const int* __restrict__ bucketCounts, int* __restrict__ bucketOffsets,
    int* __restrict__ bucketCursor, int* __restrict__ offsets, int NB, int N, int E) {
    __shared__ int sc[256];
    int t = threadIdx.x;
    int c = (t < NB) ? bucketCounts[t] : 0;
    sc[t] = c;
    __syncthreads();
    for (int off = 1; off < 256; off <<= 1) {
        int v = (t >= off) ? sc[t - off] : 0;
        __syncthreads();
        sc[t] += v;
        __syncthreads();
    }
    int excl = sc[t] - c;
    if (t < NB) { bucketOffsets[t] = excl; bucketCursor[t] = excl; }
    if (t == NB - 1) bucketOffsets[NB] = excl + c;
    if (t == 0) offsets[N] = E;
}

// Block-aggregated scatter of packed (src | dlow<<16) into bucket regions.
#define CHUNK 4096
__global__ __launch_bounds__(256) void scatter_pairs(
    const int* __restrict__ ei32, const long long* __restrict__ ei64,
    const int* __restrict__ flag, int* __restrict__ bucketCursor,
    unsigned int* __restrict__ pairs, int E) {
    __shared__ int hist[256], base[256], cur[256];
    int t = threadIdx.x;
    hist[t] = 0; cur[t] = 0;
    __syncthreads();
    int beg = blockIdx.x * CHUNK;
    int end = min(E, beg + CHUNK);
    bool is32 = (*flag) != 0;
    for (int i = beg + t; i < end; i += 256) {
        int d = is32 ? ei32[E + i] : (int)ei64[E + i];
        atomicAdd(&hist[d >> 8], 1);
    }
    __syncthreads();
    if (hist[t] > 0) base[t] = atomicAdd(&bucketCursor[t], hist[t]);
    __syncthreads();
    for (int i = beg + t; i < end; i += 256) {
        int s, d;
        if (is32) { s = ei32[i]; d = ei32[E + i]; }
        else      { s = (int)ei64[i]; d = (int)ei64[E + i]; }
        int b = d >> 8;
        int pos = base[b] + atomicAdd(&cur[b], 1);
        pairs[pos] = (unsigned int)s | ((unsigned int)(d & 255) << 16);
    }
}

// One block per bucket: counting sort by full dst; writes per-node offsets + srcs.
__global__ __launch_bounds__(256) void bucket_sort(
    const unsigned int* __restrict__ pairs, const int* __restrict__ bucketOffsets,
    int* __restrict__ offsets, int* __restrict__ srcs, int N) {
    __shared__ int cnt[256], sc[256], cur[256];
    int b = blockIdx.x, t = threadIdx.x;
    int beg = bucketOffsets[b], end = bucketOffsets[b + 1];
    cnt[t] = 0;
    __syncthreads();
    for (int i = beg + t; i < end; i += 256) atomicAdd(&cnt[(pairs[i] >> 16) & 255u], 1);
    __syncthreads();
    sc[t] = cnt[t];
    __syncthreads();
    for (int off = 1; off < 256; off <<= 1) {
        int v = (t >= off) ? sc[t - off] : 0;
        __syncthreads();
        sc[t] += v;
        __syncthreads();
    }
    int excl = sc[t] - cnt[t];
    int node = (b << 8) + t;
    if (node < N) offsets[node] = beg + excl;
    cur[t] = beg + excl;
    __syncthreads();
    for (int i = beg + t; i < end; i += 256) {
        unsigned int p = pairs[i];
        int pos = atomicAdd(&cur[(p >> 16) & 255u], 1);
        srcs[pos] = (int)(p & 0xFFFFu);
    }
}

// ---------------------------------------------------------------------------
// Prep: transpose W and fc_w into bf16 hi/lo, WT[f*64+k] = split(W[k*64+f]).
__global__ __launch_bounds__(256) void prep_weights(
    const float* __restrict__ W, const float* __restrict__ fcw,
    unsigned short* __restrict__ WTh, unsigned short* __restrict__ WTl,
    unsigned short* __restrict__ FTh, unsigned short* __restrict__ FTl) {
    for (int idx = blockIdx.x * 256 + threadIdx.x; idx < 4096; idx += gridDim.x * 256) {
        int k = idx >> 6, f = idx & 63;
        float w = W[idx];
        unsigned short hi = f2bf(w);
        WTh[f * 64 + k] = hi;
        WTl[f * 64 + k] = f2bf(w - bf2f(hi));
        float w2 = fcw[idx];
        unsigned short hi2 = f2bf(w2);
        FTh[f * 64 + k] = hi2;
        FTl[f * 64 + k] = f2bf(w2 - bf2f(hi2));
    }
}

// ---------------------------------------------------------------------------
// Split-bf16 MFMA transform: h = x@W (fp32-accurate via xh*Wh + xh*Wl + xl*Wh).
// Block = 256 thr = 4 waves; wave handles 16 nodes x 64 f (4 N-tiles).
// A[m=lane&15][k=quad*8+j]; B[k=quad*8+j][n=lane&15]; C col=lane&15, row=quad*4+reg.
// LDS WT stride 72 shorts (144 B): 16B-aligned, 4-bank lane stride (free 2-way).
__global__ __launch_bounds__(256, 4) void transform_mfma(
    const float* __restrict__ x,
    const unsigned short* __restrict__ WTh, const unsigned short* __restrict__ WTl,
    const float* __restrict__ a_src, const float* __restrict__ a_dst,  // nullable
    const float* __restrict__ bias,                                    // nullable
    unsigned short* __restrict__ hb,  // bf16 out (layers), nullable
    float* __restrict__ fout,         // fp32 out (FC), nullable
    float* __restrict__ as_, float* __restrict__ ad_, int N) {
    __shared__ __align__(16) unsigned short WThs[64 * 72];
    __shared__ __align__(16) unsigned short WTls[64 * 72];
    int tid = threadIdx.x;
    // stage WT hi/lo (64 rows x 64 shorts each) into padded LDS
    {
        int row = tid >> 2;            // 0..63
        int ch = (tid & 3) * 16;       // shorts
        uint4 h0 = ((const uint4*)(WTh + row * 64 + ch))[0];
        uint4 h1 = ((const uint4*)(WTh + row * 64 + ch))[1];
        uint4 l0 = ((const uint4*)(WTl + row * 64 + ch))[0];
        uint4 l1 = ((const uint4*)(WTl + row * 64 + ch))[1];
        *((uint4*)(WThs + row * 72 + ch)) = h0;
        *((uint4*)(WThs + row * 72 + ch + 8)) = h1;
        *((uint4*)(WTls + row * 72 + ch)) = l0;
        *((uint4*)(WTls + row * 72 + ch + 8)) = l1;
    }

    int wid = tid >> 6;
    int lane = tid & 63;
    int col = lane & 15;
    int quad = lane >> 4;
    int mbase = blockIdx.x * 64 + wid * 16;

    // A fragments (hi/lo) for both K-steps, loaded straight from global x.
    bf16x8 Ah[2], Al[2];
    int arow = mbase + col;
    const float* xr = x + (size_t)(arow < N ? arow : 0) * FDIM + quad * 8;
#pragma unroll
    for (int ks = 0; ks < 2; ks++) {
        float4 xa = *(const float4*)(xr + ks * 32);
        float4 xb = *(const float4*)(xr + ks * 32 + 4);
        float xv[8] = {xa.x, xa.y, xa.z, xa.w, xb.x, xb.y, xb.z, xb.w};
#pragma unroll
        for (int e = 0; e < 8; e++) {
            unsigned short hi = f2bf(xv[e]);
            Ah[ks][e] = (short)hi;
            Al[ks][e] = (short)f2bf(xv[e] - bf2f(hi));
        }
    }
    __syncthreads();

    f32x4 acc[4];
#pragma unroll
    for (int ft = 0; ft < 4; ft++) acc[ft] = (f32x4){0.f, 0.f, 0.f, 0.f};

#pragma unroll
    for (int ft = 0; ft < 4; ft++) {
        int f = ft * 16 + col;
#pragma unroll
        for (int ks = 0; ks < 2; ks++) {
            int off = f * 72 + ks * 32 + quad * 8;
            bf16x8 Bh = *(const bf16x8*)(WThs + off);
            bf16x8 Bl = *(const bf16x8*)(WTls + off);
            acc[ft] = __builtin_amdgcn_mfma_f32_16x16x32_bf16(Ah[ks], Bh, acc[ft], 0, 0, 0);
            acc[ft] = __builtin_amdgcn_mfma_f32_16x16x32_bf16(Ah[ks], Bl, acc[ft], 0, 0, 0);
            acc[ft] = __builtin_amdgcn_mfma_f32_16x16x32_bf16(Al[ks], Bh, acc[ft], 0, 0, 0);
        }
    }

    if (fout) {
#pragma unroll
        for (int ft = 0; ft < 4; ft++) {
            int f = ft * 16 + col;
            float bv = bias ? bias[f] : 0.f;
#pragma unroll
            for (int r = 0; r < 4; r++) {
                int node = mbase + quad * 4 + r;
                if (node < N) fout[(size_t)node * FDIM + f] = acc[ft][r] + bv;
            }
        }
    }
    if (hb) {
#pragma unroll
        for (int ft = 0; ft < 4; ft++) {
            int f = ft * 16 + col;
#pragma unroll
            for (int r = 0; r < 4; r++) {
                int node = mbase + quad * 4 + r;
                if (node < N) hb[(size_t)node * FDIM + f] = f2bf(acc[ft][r]);
            }
        }
    }
    if (as_) {
        float asv[4], adv[4];
#pragma unroll
        for (int ft = 0; ft < 4; ft++) {
            asv[ft] = a_src[ft * 16 + col];
            adv[ft] = a_dst[ft * 16 + col];
        }
#pragma unroll
        for (int r = 0; r < 4; r++) {
            float pa = 0.f, pd = 0.f;
#pragma unroll
            for (int ft = 0; ft < 4; ft++) {
                pa = fmaf(acc[ft][r], asv[ft], pa);
                pd = fmaf(acc[ft][r], adv[ft], pd);
            }
#pragma unroll
            for (int off = 1; off <= 8; off <<= 1) {
                pa += __shfl_xor(pa, off, 64);
                pd += __shfl_xor(pd, off, 64);
            }
            int node = mbase + quad * 4 + r;
            if (col == 0 && node < N) { as_[node] = pa; ad_[node] = pd; }
        }
    }
}

// ---------------------------------------------------------------------------
// One wave per dst node, single pass (logits bounded, fp32 exp safe).
// 4 edges x 16 lanes, bf16 ushort4 h-row loads, 4-deep unroll for MLP.
__global__ __launch_bounds__(256) void gat_gather(
    const unsigned short* __restrict__ hb,
    const float* __restrict__ as_, const float* __restrict__ ad_,
    const int* __restrict__ offsets, const int* __restrict__ srcs,
    const float* __restrict__ bvec, const float* __restrict__ x0,
    float* __restrict__ xout, int N) {
    int wid = (blockIdx.x * blockDim.x + threadIdx.x) >> 6;
    if (wid >= N) return;
    int lane = threadIdx.x & 63;
    int g = lane >> 4;      // edge slot 0..3
    int q = lane & 15;      // feature quad 0..15
    int beg = offsets[wid], end = offsets[wid + 1];
    float adv = ad_[wid];

    float4 acc = {0.f, 0.f, 0.f, 0.f};
    float denom = 0.f;
    const unsigned short* hq = hb + (q << 2);

#define SLOT(J)                                                              \
    {                                                                        \
        int j_ = (J);                                                        \
        float exj = __shfl(ex, j_, 64);                                      \
        int sj = __shfl(s, j_, 64);                                          \
        ushort4 hv = *(const ushort4*)(hq + (size_t)sj * FDIM);              \
        acc.x = fmaf(exj, bf2f(hv.x), acc.x);                                \
        acc.y = fmaf(exj, bf2f(hv.y), acc.y);                                \
        acc.z = fmaf(exj, bf2f(hv.z), acc.z);                                \
        acc.w = fmaf(exj, bf2f(hv.w), acc.w);                                \
    }

    for (int cbeg = beg; cbeg < end; cbeg += 64) {
        int i = cbeg + lane;
        float ex = 0.f;
        int s = 0;
        if (i < end) {
            s = srcs[i];
            float e = as_[s] + adv;
            e = e > 0.f ? e : NEG_SLOPE * e;
            ex = __expf(e);
        }
        denom += ex;
        int cnt = min(64, end - cbeg);
        int njj = (cnt + 3) >> 2;
        int jj = 0;
        for (; jj + 4 <= njj; jj += 4) {
            int j0 = (jj << 2) | g;
            SLOT(j0); SLOT(j0 + 4); SLOT(j0 + 8); SLOT(j0 + 12);
        }
        for (; jj < njj; jj++) {
            SLOT((jj << 2) | g);
        }
    }
#undef SLOT

#pragma unroll
    for (int off = 32; off; off >>= 1) denom += __shfl_xor(denom, off, 64);
#pragma unroll
    for (int off = 16; off <= 32; off <<= 1) {
        acc.x += __shfl_xor(acc.x, off, 64);
        acc.y += __shfl_xor(acc.y, off, 64);
        acc.z += __shfl_xor(acc.z, off, 64);
        acc.w += __shfl_xor(acc.w, off, 64);
    }
    if (g == 0) {
        float inv = denom > 0.f ? 1.f / denom : 0.f;
        float4 b4 = *(const float4*)(bvec + (q << 2));
        float4 xv = *(const float4*)(x0 + (size_t)wid * FDIM + (q << 2));
        float4 o;
        o.x = BETA * (acc.x * inv + b4.x) + (1.f - BETA) * xv.x;
        o.y = BETA * (acc.y * inv + b4.y) + (1.f - BETA) * xv.y;
        o.z = BETA * (acc.z * inv + b4.z) + (1.f - BETA) * xv.z;
        o.w = BETA * (acc.w * inv + b4.w) + (1.f - BETA) * xv.w;
        *(float4*)(xout + (size_t)wid * FDIM + (q << 2)) = o;
    }
}

// ---------------------------------------------------------------------------
extern "C" void kernel_launch(void* const* d_in, const int* in_sizes, int n_in,
                              void* d_out, int out_size, void* d_ws, size_t ws_size,
                              hipStream_t stream) {
    const int N = N_NODES;
    const int E = in_sizes[1] / 2;
    const int NB = (N + 255) >> 8;   // 196 buckets

    const float* x     = (const float*)d_in[0];
    const void*  ei    = d_in[1];
    const float* W     = (const float*)d_in[2];
    const float* a_src = (const float*)d_in[3];
    const float* a_dst = (const float*)d_in[4];
    const float* bvec  = (const float*)d_in[5];
    const float* fc_w  = (const float*)d_in[6];
    const float* fc_b  = (const float*)d_in[7];

    float* out = (float*)d_out;                 // [N, F]
    float* x3  = out + (size_t)N * FDIM;        // [N, F] (second output = h)

    char* p = (char*)d_ws;
    auto alloc = [&](size_t bytes) -> void* {
        void* r = (void*)p;
        p += (bytes + 255) & ~(size_t)255;
        return r;
    };
    int*            flag     = (int*)alloc(256);
    int*            bCounts  = (int*)alloc(256 * 4);
    int*            bOffsets = (int*)alloc(257 * 4);
    int*            bCursor  = (int*)alloc(256 * 4);
    unsigned int*   pairs    = (unsigned int*)alloc((size_t)E * 4);
    int*            srcs     = (int*)alloc((size_t)E * 4);
    int*            offsets  = (int*)alloc((size_t)(N + 1) * 4);
    float*          as_      = (float*)alloc((size_t)N * 4);
    float*          ad_      = (float*)alloc((size_t)N * 4);
    unsigned short* hbuf     = (unsigned short*)alloc((size_t)N * FDIM * 2);
    float*          xbuf     = (float*)alloc((size_t)N * FDIM * 4);
    unsigned short* WTh      = (unsigned short*)alloc(4096 * 2);
    unsigned short* WTl      = (unsigned short*)alloc(4096 * 2);
    unsigned short* FTh      = (unsigned short*)alloc(4096 * 2);
    unsigned short* FTl      = (unsigned short*)alloc(4096 * 2);

    hipMemsetAsync(flag, 0, 4, stream);
    hipMemsetAsync(bCounts, 0, 256 * 4, stream);

    const int nCheck = 65536;
    detect_kernel<<<nCheck / 256, 256, 0, stream>>>((const unsigned int*)ei, flag, nCheck);

    prep_weights<<<16, 256, 0, stream>>>(W, fc_w, WTh, WTl, FTh, FTl);

    hist_kernel<<<512, 256, 0, stream>>>((const int*)ei, (const long long*)ei, flag, bCounts, E);
    bucket_scan<<<1, 256, 0, stream>>>(bCounts, bOffsets, bCursor, offsets, NB, N, E);
    scatter_pairs<<<(E + CHUNK - 1) / CHUNK, 256, 0, stream>>>(
        (const int*)ei, (const long long*)ei, flag, bCursor, pairs, E);
    bucket_sort<<<NB, 256, 0, stream>>>(pairs, bOffsets, offsets, srcs, N);

    int tgrid = (N + 63) / 64;
    int ggrid = (N * 64 + 255) / 256;

    // layer 1
    transform_mfma<<<tgrid, 256, 0, stream>>>(x, WTh, WTl, a_src, a_dst, nullptr,
                                              hbuf, nullptr, as_, ad_, N);
    gat_gather<<<ggrid, 256, 0, stream>>>(hbuf, as_, ad_, offsets, srcs, bvec, x, xbuf, N);
    // layer 2
    transform_mfma<<<tgrid, 256, 0, stream>>>(xbuf, WTh, WTl, a_src, a_dst, nullptr,
                                              hbuf, nullptr, as_, ad_, N);
    gat_gather<<<ggrid, 256, 0, stream>>>(hbuf, as_, ad_, offsets, srcs, bvec, x, xbuf, N);
    // layer 3
    transform_mfma<<<tgrid, 256, 0, stream>>>(xbuf, WTh, WTl, a_src, a_dst, nullptr,
                                              hbuf, nullptr, as_, ad_, N);
    gat_gather<<<ggrid, 256, 0, stream>>>(hbuf, as_, ad_, offsets, srcs, bvec, x, x3, N);
    // final fc: out = x3 @ fc_w + fc_b
    transform_mfma<<<tgrid, 256, 0, stream>>>(x3, FTh, FTl, nullptr, nullptr, fc_b,
                                              nullptr, out, nullptr, nullptr, N);
}